// Round 3
// baseline (478.642 us; speedup 1.0000x reference)
//
#include <hip/hip_runtime.h>

#define B_   32
#define C_   64
#define H_   128
#define W_   128
#define HW_  (H_ * W_)       // 16384
#define CHW_ (C_ * HW_)      // 1048576

typedef _Float16 half8 __attribute__((ext_vector_type(8)));
typedef float f32x4 __attribute__((ext_vector_type(4)));

static __device__ inline ushort f2h(float f) {
    union { _Float16 h; ushort u; } cv;
    cv.h = (_Float16)f;
    return cv.u;
}

// Fused: box-mean(3x3, edge-clipped) -> 1x1 conv (64x64) -> residual add.
// MFMA version. Block = 4 INDEPENDENT waves (no barriers). Wave owns one
// image row (2 chunks of 64 px). Per chunk:
//   filter -> f16 A-buffer [px][c] (wave-private 8 KB LDS, XOR-swizzled)
//   matmul: out[px][o] = A[px][c] * W[c][o] via mfma_f32_16x16x32_f16,
//   W held in registers as 8 B-fragments (loaded once from global).
//   Residual+bias folded into fp32 accumulator init (C-frag layout:
//   o = n*16 + (lane&15), px = m*16 + 4*(lane>>4) + reg -> float4-able).
// LDS traffic drops ~50x vs scalar matmul; VALU FMA work moves to MFMA pipe.
__global__ __launch_bounds__(256, 4) void denoise_fused(
    const float* __restrict__ x, const float* __restrict__ cw,
    const float* __restrict__ cb, float* __restrict__ out)
{
    __shared__ ushort Abuf[4][64 * 64];   // 32 KB total: per-wave f16 [px][c]

    const int t    = threadIdx.x;
    const int lane = t & 63;
    const int wid  = t >> 6;
    const int r    = lane & 15;            // px f4-index (filter) / o-col (mma)
    const int g    = lane >> 4;            // 0..3

    // XCD-aware swizzle: 1024 blocks, 8 XCDs -> 128 consecutive work-ids per
    // XCD (= 4 batches) for boundary-row L2 reuse. nwg%8==0 -> bijective.
    const int work   = (blockIdx.x & 7) * 128 + (blockIdx.x >> 3);
    const int row_id = work * 4 + wid;     // 0..4095, 4 consecutive rows/block
    const int b = row_id >> 7;
    const int h = row_id & 127;

    const float* xb = x   + (size_t)b * CHW_;
    float*       ob = out + (size_t)b * CHW_;

    // ---- Weights -> registers as f16 B-frags. frag[k][n]: this lane holds
    // B[c = k*32 + g*8 + {0..7}][o = n*16 + r]  (cw is [o][c] row-major).
    half8 Wf[2][4];
    #pragma unroll
    for (int k = 0; k < 2; ++k)
        #pragma unroll
        for (int n = 0; n < 4; ++n) {
            const float* wp = cw + (n * 16 + r) * 64 + k * 32 + g * 8;
            float4 w0 = *(const float4*)wp;
            float4 w1 = *(const float4*)(wp + 4);
            half8 hh;
            hh[0] = (_Float16)w0.x; hh[1] = (_Float16)w0.y;
            hh[2] = (_Float16)w0.z; hh[3] = (_Float16)w0.w;
            hh[4] = (_Float16)w1.x; hh[5] = (_Float16)w1.y;
            hh[6] = (_Float16)w1.z; hh[7] = (_Float16)w1.w;
            Wf[k][n] = hh;
        }

    float bias4[4];
    #pragma unroll
    for (int n = 0; n < 4; ++n) bias4[n] = cb[n * 16 + r];

    const bool hm = (h > 0), hp = (h < H_ - 1);
    const float rv = 1.f + (hm ? 1.f : 0.f) + (hp ? 1.f : 0.f);
    const float i3 = 1.f / (rv * 3.f);
    const float i2 = 1.f / (rv * 2.f);

    ushort* A = Abuf[wid];

    #pragma unroll
    for (int q = 0; q < 2; ++q) {
        // ---- Filter: 16 passes x (4 g-groups) = 64 channels -> A[px][c] ----
        #pragma unroll
        for (int p = 0; p < 16; ++p) {
            const int c = g * 16 + p;
            const float* rc = xb + c * HW_ + h * W_ + q * 64;
            float4 v = ((const float4*)rc)[r];
            if (hm) { float4 a = ((const float4*)(rc - W_))[r]; v.x += a.x; v.y += a.y; v.z += a.z; v.w += a.w; }
            if (hp) { float4 a = ((const float4*)(rc + W_))[r]; v.x += a.x; v.y += a.y; v.z += a.z; v.w += a.w; }
            // horizontal neighbors via shfl; 16-group crossings are exactly
            // the r==0 / r==15 lanes, which are masked or recomputed below
            float L = __shfl_up(v.w, 1);
            float R = __shfl_down(v.x, 1);
            if (q == 0 && r == 15) {          // chunk edge: real px64 exists
                const float* rb = rc + 64;
                float vr = rb[0];
                if (hm) vr += rb[-W_];
                if (hp) vr += rb[W_];
                R = vr;
            }
            if (q == 1 && r == 0) {           // chunk edge: real px63 exists
                const float* lb = rc - 1;
                float vl = lb[0];
                if (hm) vl += lb[-W_];
                if (hp) vl += lb[W_];
                L = vl;
            }
            float d4[4];
            d4[0] = (q == 0 && r == 0)  ? (v.x + v.y) * i2 : (L + v.x + v.y) * i3;
            d4[1] = (v.x + v.y + v.z) * i3;
            d4[2] = (v.y + v.z + v.w) * i3;
            d4[3] = (q == 1 && r == 15) ? (v.z + v.w) * i2 : (v.z + v.w + R) * i3;
            // scatter 4 f16 into A[px][c], px = 4r+e, 16B-slot XOR swizzle
            #pragma unroll
            for (int e = 0; e < 4; ++e) {
                const int px = 4 * r + e;
                const int pp = (px ^ (px >> 3)) & 7;
                A[px * 64 + (c ^ (pp << 3))] = f2h(d4[e]);
            }
        }

        // ---- Accumulator init: residual x (fp32, L2-hot) + bias ----
        // C-frag layout: o = n*16 + r (col), px = m*16 + 4*g + reg (row)
        f32x4 acc[4][4];   // [m][n]
        #pragma unroll
        for (int n = 0; n < 4; ++n) {
            const int o = n * 16 + r;
            #pragma unroll
            for (int m = 0; m < 4; ++m) {
                const float* rp = xb + o * HW_ + h * W_ + q * 64 + m * 16 + 4 * g;
                float4 xr = *(const float4*)rp;
                f32x4 a;
                a[0] = xr.x + bias4[n]; a[1] = xr.y + bias4[n];
                a[2] = xr.z + bias4[n]; a[3] = xr.w + bias4[n];
                acc[m][n] = a;
            }
        }

        // ---- MFMA: 4m x 4n x 2k = 32 per chunk; A-frags 8 x ds_read_b128 --
        #pragma unroll
        for (int k = 0; k < 2; ++k) {
            half8 Af[4];
            #pragma unroll
            for (int m = 0; m < 4; ++m) {
                const int px = m * 16 + r;          // A-frag row = lane&15
                const int pp = (px ^ (px >> 3)) & 7;
                const int slot = (4 * k + g) ^ pp;  // k-octet = lane>>4
                Af[m] = *(const half8*)&A[px * 64 + slot * 8];
            }
            #pragma unroll
            for (int n = 0; n < 4; ++n)
                #pragma unroll
                for (int m = 0; m < 4; ++m)
                    acc[m][n] = __builtin_amdgcn_mfma_f32_16x16x32_f16(
                        Af[m], Wf[k][n], acc[m][n], 0, 0, 0);
        }

        // ---- Store: float4 per C-frag, 64 B segments per channel ----
        #pragma unroll
        for (int n = 0; n < 4; ++n) {
            const int o = n * 16 + r;
            #pragma unroll
            for (int m = 0; m < 4; ++m) {
                float* op = ob + o * HW_ + h * W_ + q * 64 + m * 16 + 4 * g;
                float4 res;
                res.x = acc[m][n][0]; res.y = acc[m][n][1];
                res.z = acc[m][n][2]; res.w = acc[m][n][3];
                *(float4*)op = res;
            }
        }
        // next chunk reuses A: same-wave LDS deps handled by compiler waits
    }
}

extern "C" void kernel_launch(void* const* d_in, const int* in_sizes, int n_in,
                              void* d_out, int out_size, void* d_ws, size_t ws_size,
                              hipStream_t stream) {
    const float* x  = (const float*)d_in[0];
    const float* cw = (const float*)d_in[1];
    const float* cb = (const float*)d_in[2];
    float* out = (float*)d_out;
    dim3 grid(1024);    // 4096 row-waves; 4 blocks/CU co-resident
    dim3 block(256);
    hipLaunchKernelGGL(denoise_fused, grid, block, 0, stream, x, cw, cb, out);
}

// Round 5
// 380.768 us; speedup vs baseline: 1.2570x; 1.2570x over previous
//
#include <hip/hip_runtime.h>

#define B_   32
#define C_   64
#define H_   128
#define W_   128
#define HW_  (H_ * W_)       // 16384
#define CHW_ (C_ * HW_)      // 1048576

typedef _Float16 half8 __attribute__((ext_vector_type(8)));
typedef float f32x4 __attribute__((ext_vector_type(4)));

static __device__ inline uint f2h(float f) {
    union { _Float16 h; ushort u; } cv;
    cv.h = (_Float16)f;
    return (uint)cv.u;
}

// Fused: box-mean(3x3, edge-clipped) -> 1x1 conv (64x64) -> residual add.
// MFMA version, spill-fixed. Block = 4 INDEPENDENT waves (no barriers).
// Wave owns one image row (2 chunks of 64 px). Per chunk:
//   filter -> f16 A-buffer [px][c] (wave-private 8 KB LDS, XOR-swizzled,
//   channel-PAIRED b32 writes)
//   matmul: out[px][o] = A[px][c] * W[c][o] via mfma_f32_16x16x32_f16,
//   W held in registers as 8 B-fragments (loaded once from global).
//   Residual+bias folded into fp32 accumulator init (C-frag layout:
//   o = n*16 + (lane&15), px = m*16 + 4*(lane>>4) + reg -> float4-able).
// Register budget: acc 64 (AGPR) + Wf 32 + ~40 misc ~= 140; launch_bounds
// (256,3) caps at 170 -> NO SPILL (round-3's (256,4)=128 cap spilled acc,
// +215 MB of scratch HBM traffic, 335 us).
__global__ __launch_bounds__(256, 3) void denoise_fused(
    const float* __restrict__ x, const float* __restrict__ cw,
    const float* __restrict__ cb, float* __restrict__ out)
{
    __shared__ ushort Abuf[4][64 * 64];   // 32 KB total: per-wave f16 [px][c]

    const int t    = threadIdx.x;
    const int lane = t & 63;
    const int wid  = t >> 6;
    const int r    = lane & 15;            // px f4-index (filter) / o-col (mma)
    const int g    = lane >> 4;            // 0..3

    // XCD-aware swizzle: 1024 blocks, 8 XCDs -> 128 consecutive work-ids per
    // XCD (= 4 batches) for boundary-row L2 reuse. nwg%8==0 -> bijective.
    const int work   = (blockIdx.x & 7) * 128 + (blockIdx.x >> 3);
    const int row_id = work * 4 + wid;     // 0..4095, 4 consecutive rows/block
    const int b = row_id >> 7;
    const int h = row_id & 127;

    const float* xb = x   + (size_t)b * CHW_;
    float*       ob = out + (size_t)b * CHW_;

    // ---- Weights -> registers as f16 B-frags. frag[k][n]: this lane holds
    // B[c = k*32 + g*8 + {0..7}][o = n*16 + r]  (cw is [o][c] row-major).
    half8 Wf[2][4];
    #pragma unroll
    for (int k = 0; k < 2; ++k)
        #pragma unroll
        for (int n = 0; n < 4; ++n) {
            const float* wp = cw + (n * 16 + r) * 64 + k * 32 + g * 8;
            float4 w0 = *(const float4*)wp;
            float4 w1 = *(const float4*)(wp + 4);
            half8 hh;
            hh[0] = (_Float16)w0.x; hh[1] = (_Float16)w0.y;
            hh[2] = (_Float16)w0.z; hh[3] = (_Float16)w0.w;
            hh[4] = (_Float16)w1.x; hh[5] = (_Float16)w1.y;
            hh[6] = (_Float16)w1.z; hh[7] = (_Float16)w1.w;
            Wf[k][n] = hh;
        }

    float bias4[4];
    #pragma unroll
    for (int n = 0; n < 4; ++n) bias4[n] = cb[n * 16 + r];

    const bool hm = (h > 0), hp = (h < H_ - 1);
    const float rv = 1.f + (hm ? 1.f : 0.f) + (hp ? 1.f : 0.f);
    const float i3 = 1.f / (rv * 3.f);
    const float i2 = 1.f / (rv * 2.f);

    ushort* A = Abuf[wid];

    #pragma unroll
    for (int q = 0; q < 2; ++q) {
        // ---- Filter: 8 pair-passes x 4 g-groups = 64 channels -> A[px][c],
        //      two adjacent channels packed per b32 LDS write ----
        #pragma unroll
        for (int p2 = 0; p2 < 8; ++p2) {
            const int c = g * 16 + p2 * 2;    // even
            uint pack[4];
            #pragma unroll
            for (int pc = 0; pc < 2; ++pc) {
                const float* rc = xb + (c + pc) * HW_ + h * W_ + q * 64;
                float4 v = ((const float4*)rc)[r];
                if (hm) { float4 a = ((const float4*)(rc - W_))[r]; v.x += a.x; v.y += a.y; v.z += a.z; v.w += a.w; }
                if (hp) { float4 a = ((const float4*)(rc + W_))[r]; v.x += a.x; v.y += a.y; v.z += a.z; v.w += a.w; }
                // horizontal neighbors via shfl; 16-group crossings are
                // exactly the r==0 / r==15 lanes: masked or recomputed
                float L = __shfl_up(v.w, 1);
                float R = __shfl_down(v.x, 1);
                if (q == 0 && r == 15) {          // chunk edge: real px64
                    const float* rb = rc + 64;
                    float vr = rb[0];
                    if (hm) vr += rb[-W_];
                    if (hp) vr += rb[W_];
                    R = vr;
                }
                if (q == 1 && r == 0) {           // chunk edge: real px63
                    const float* lb = rc - 1;
                    float vl = lb[0];
                    if (hm) vl += lb[-W_];
                    if (hp) vl += lb[W_];
                    L = vl;
                }
                float d0 = (q == 0 && r == 0)  ? (v.x + v.y) * i2 : (L + v.x + v.y) * i3;
                float d1 = (v.x + v.y + v.z) * i3;
                float d2 = (v.y + v.z + v.w) * i3;
                float d3 = (q == 1 && r == 15) ? (v.z + v.w) * i2 : (v.z + v.w + R) * i3;
                if (pc == 0) {
                    pack[0] = f2h(d0); pack[1] = f2h(d1);
                    pack[2] = f2h(d2); pack[3] = f2h(d3);
                } else {
                    pack[0] |= f2h(d0) << 16; pack[1] |= f2h(d1) << 16;
                    pack[2] |= f2h(d2) << 16; pack[3] |= f2h(d3) << 16;
                }
            }
            #pragma unroll
            for (int e = 0; e < 4; ++e) {
                const int px = 4 * r + e;
                const int pp = (px ^ (px >> 3)) & 7;
                // c even; XOR touches bits >=3 only -> (c^..., c^...+1) pair
                *(uint*)&A[px * 64 + (c ^ (pp << 3))] = pack[e];
            }
        }

        // ---- Accumulator init: residual x (fp32, L2-hot) + bias ----
        // C-frag layout: o = n*16 + r (col), px = m*16 + 4*g + reg (row)
        f32x4 acc[4][4];   // [m][n] -> AGPRs
        #pragma unroll
        for (int n = 0; n < 4; ++n) {
            #pragma unroll
            for (int m = 0; m < 4; ++m) {
                const float* rp = xb + (n * 16 + r) * HW_ + h * W_ + q * 64 + m * 16 + 4 * g;
                float4 xr = *(const float4*)rp;
                f32x4 a;
                a[0] = xr.x + bias4[n]; a[1] = xr.y + bias4[n];
                a[2] = xr.z + bias4[n]; a[3] = xr.w + bias4[n];
                acc[m][n] = a;
            }
        }

        // ---- MFMA: 2k x 4m x 4n = 32 per chunk; one A-frag live at a time --
        #pragma unroll
        for (int k = 0; k < 2; ++k) {
            #pragma unroll
            for (int m = 0; m < 4; ++m) {
                const int px = m * 16 + r;          // A-frag row = lane&15
                const int pp = (px ^ (px >> 3)) & 7;
                const int slot = (4 * k + g) ^ pp;  // k-octet = lane>>4
                half8 Af = *(const half8*)&A[px * 64 + slot * 8];
                #pragma unroll
                for (int n = 0; n < 4; ++n)
                    acc[m][n] = __builtin_amdgcn_mfma_f32_16x16x32_f16(
                        Af, Wf[k][n], acc[m][n], 0, 0, 0);
            }
        }

        // ---- Store: float4 per C-frag, 64 B segments per channel ----
        #pragma unroll
        for (int n = 0; n < 4; ++n) {
            #pragma unroll
            for (int m = 0; m < 4; ++m) {
                float* op = ob + (n * 16 + r) * HW_ + h * W_ + q * 64 + m * 16 + 4 * g;
                float4 res;
                res.x = acc[m][n][0]; res.y = acc[m][n][1];
                res.z = acc[m][n][2]; res.w = acc[m][n][3];
                *(float4*)op = res;
            }
        }
        // next chunk reuses A: same-wave LDS deps handled by compiler waits
    }
}

extern "C" void kernel_launch(void* const* d_in, const int* in_sizes, int n_in,
                              void* d_out, int out_size, void* d_ws, size_t ws_size,
                              hipStream_t stream) {
    const float* x  = (const float*)d_in[0];
    const float* cw = (const float*)d_in[1];
    const float* cb = (const float*)d_in[2];
    float* out = (float*)d_out;
    dim3 grid(1024);    // 4096 row-waves
    dim3 block(256);
    hipLaunchKernelGGL(denoise_fused, grid, block, 0, stream, x, cw, cb, out);
}